// Round 6
// baseline (245.788 us; speedup 1.0000x reference)
//
#include <hip/hip_runtime.h>
#include <cstdint>
#include <cstddef>

#define B_ 2
#define S_ 4096
#define D_ 1024
#define H_ 16
#define HD_ 64
#define NB_ 64
#define W_ 8
#define M_ (B_*S_)   // 8192

// 0.125 (1/sqrt(HD)) * log2(e), folded into Q so attention softmax = exp2(S)
#define QSCALE 0.18033688011112042f
#define LOG2_10000_OVER_32 0.41524101186092034f

typedef __bf16 bf16_t;
typedef __bf16 bf16x8 __attribute__((ext_vector_type(8)));
typedef float f32x4 __attribute__((ext_vector_type(4)));

#define GLOAD_LDS16(gp, lp) \
  __builtin_amdgcn_global_load_lds((__attribute__((address_space(1))) void*)(gp), \
                                   (__attribute__((address_space(3))) void*)(lp), 16, 0, 0)

// ---------------- fp32 -> bf16 cast (hidden states) ----------------
__global__ void cast_bf16_kernel(const float* __restrict__ x, bf16_t* __restrict__ y, int n4) {
  int i = blockIdx.x * 256 + threadIdx.x;
  if (i >= n4) return;
  float4 v = ((const float4*)x)[i];
  union { bf16_t b[4]; uint2 u; } cv;
  cv.b[0] = (bf16_t)v.x; cv.b[1] = (bf16_t)v.y; cv.b[2] = (bf16_t)v.z; cv.b[3] = (bf16_t)v.w;
  ((uint2*)y)[i] = cv.u;
}

// ---------------- weight transpose + cast: wT[n][k] = (bf16)w[k][n] ----------------
__global__ void transpose_cast_kernel(const float* __restrict__ w0, const float* __restrict__ w1,
                                      const float* __restrict__ w2, const float* __restrict__ w3,
                                      bf16_t* __restrict__ out) {
  const float* w = (blockIdx.z == 0) ? w0 : (blockIdx.z == 1) ? w1 : (blockIdx.z == 2) ? w2 : w3;
  bf16_t* wt = out + (size_t)blockIdx.z * D_ * D_;
  __shared__ float tile[32][33];
  int x = blockIdx.x * 32 + threadIdx.x;
  int y0 = blockIdx.y * 32;
  for (int i = threadIdx.y; i < 32; i += 8)
    tile[i][threadIdx.x] = w[(size_t)(y0 + i) * D_ + x];
  __syncthreads();
  int x2 = blockIdx.y * 32 + threadIdx.x;   // k
  int y2 = blockIdx.x * 32;                 // n base
  for (int i = threadIdx.y; i < 32; i += 8)
    wt[(size_t)(y2 + i) * D_ + x2] = (bf16_t)tile[threadIdx.x][i];
}

// ---------------- GEMM: C[M,1024] = A[M,1024] @ Bt[n][k]^T ----------------
// OBF=true:  z=0 -> Q (rope+QSCALE fused), z=1 -> K (rope), z=2 -> V transposed+permuted to vt_out
// OBF=false: fp32 output
// Epilogues for q/k and fp32 are LDS-bounced: reg -> per-wave LDS slice (stride 68 f32,
// conflict-free, 16B-aligned rows) -> contiguous vector stores (128/256-B segments).
template<bool OBF>
__global__ __launch_bounds__(256) void gemm128(const bf16_t* __restrict__ A,
                                               const bf16_t* __restrict__ BtBase,
                                               void* __restrict__ Cbase,
                                               bf16_t* __restrict__ vt_out,
                                               const int* __restrict__ pos_ids) {
  const bf16_t* Bt = BtBase + (size_t)blockIdx.z * D_ * D_;
  const int mb = blockIdx.y * 128, nb = blockIdx.x * 128;
  const int tid = threadIdx.x;
  const int wid = tid >> 6, lane = tid & 63;
  const int quad = lane >> 4, l16 = lane & 15;
  const int wr = wid >> 1, wc = wid & 1;

  // union: staging (As 8K + Bs 8K) vs epilogue bounce (4 waves x 4352 B)
  __shared__ __align__(16) char smem[17408];
  bf16_t* As = (bf16_t*)smem;
  bf16_t* Bs = (bf16_t*)(smem + 8192);
  float*  Lw = (float*)(smem + (size_t)wid * 4352);

  f32x4 acc[4][4];
#pragma unroll
  for (int mi = 0; mi < 4; ++mi)
#pragma unroll
    for (int ni = 0; ni < 4; ++ni)
      acc[mi][ni] = (f32x4){0.f, 0.f, 0.f, 0.f};

  const int acol = (lane & 3) * 8;
  const int arow0 = wid * 32 + (lane >> 2);
  const bf16_t* gA = A + (size_t)(mb + arow0) * D_ + acol;
  const bf16_t* gB = Bt + (size_t)(nb + arow0) * D_ + acol;

  for (int kt = 0; kt < 32; ++kt) {
    const int k0 = kt * 32;
    __syncthreads();
#pragma unroll
    for (int c = 0; c < 2; ++c) {
      GLOAD_LDS16(gA + (size_t)c * 16 * D_ + k0, As + (wid * 2 + c) * 512);
      GLOAD_LDS16(gB + (size_t)c * 16 * D_ + k0, Bs + (wid * 2 + c) * 512);
    }
    __syncthreads();
    bf16x8 af[4], bfr[4];
#pragma unroll
    for (int mi = 0; mi < 4; ++mi)
      af[mi] = *(const bf16x8*)&As[(wr * 64 + mi * 16 + l16) * 32 + quad * 8];
#pragma unroll
    for (int ni = 0; ni < 4; ++ni)
      bfr[ni] = *(const bf16x8*)&Bs[(wc * 64 + ni * 16 + l16) * 32 + quad * 8];
#pragma unroll
    for (int mi = 0; mi < 4; ++mi)
#pragma unroll
      for (int ni = 0; ni < 4; ++ni)
        acc[mi][ni] = __builtin_amdgcn_mfma_f32_16x16x32_bf16(af[mi], bfr[ni], acc[mi][ni], 0, 0, 0);
  }

  __syncthreads();   // all LDS frag reads done before epilogue reuses smem

  if constexpr (OBF) {
    if (blockIdx.z < 2) {
      bf16_t* Cp = (bf16_t*)Cbase + (size_t)blockIdx.z * M_ * D_;
      const float qsc = (blockIdx.z == 0) ? QSCALE : 1.0f;
      float invf[2];
#pragma unroll
      for (int ni = 0; ni < 2; ++ni)
        invf[ni] = __builtin_exp2f(-(float)(ni * 16 + l16) * LOG2_10000_OVER_32);
#pragma unroll
      for (int mi = 0; mi < 4; ++mi) {
        // rotate into per-wave LDS slice (16 rows x 64 cols, stride 68)
#pragma unroll
        for (int r = 0; r < 4; ++r) {
          int row = mb + wr * 64 + mi * 16 + quad * 4 + r;
          float fpos = (float)pos_ids[row];
#pragma unroll
          for (int ni = 0; ni < 2; ++ni) {
            float sn, cs;
            __sincosf(fpos * invf[ni], &sn, &cs);
            float x1 = acc[mi][ni][r], x2 = acc[mi][ni + 2][r];
            Lw[(quad * 4 + r) * 68 + ni * 16 + l16]      = (x1 * cs - x2 * sn) * qsc;
            Lw[(quad * 4 + r) * 68 + ni * 16 + l16 + 32] = (x2 * cs + x1 * sn) * qsc;
          }
        }
        // copy-out: 4 bf16 per lane, 128-B segments per 16 lanes
#pragma unroll
        for (int j = 0; j < 4; ++j) {
          int lr = j * 4 + quad;
          f32x4 vv = *(const f32x4*)&Lw[lr * 68 + l16 * 4];
          union { bf16_t b[4]; uint2 u; } ob;
#pragma unroll
          for (int i = 0; i < 4; ++i) ob.b[i] = (bf16_t)vv[i];
          int rowg = mb + wr * 64 + mi * 16 + lr;
          int colg = nb + wc * 64 + l16 * 4;
          *(uint2*)&Cp[(size_t)rowg * D_ + colg] = ob.u;
        }
      }
    } else {
      // V: transposed + pi-permuted, contiguous uint4 stores (unchanged)
      int g = 2 * blockIdx.y + wr;
      int bb = g >> 6, sblk = g & 63;
      int hh = 2 * blockIdx.x + wc;
      size_t vbase = (size_t)(bb * H_ + hh) * HD_ * S_;
#pragma unroll
      for (int ni = 0; ni < 4; ++ni) {
        int d = ni * 16 + l16;
        union { bf16_t bv[16]; uint4 u[2]; } pk;
#pragma unroll
        for (int r = 0; r < 4; ++r)
#pragma unroll
          for (int mi = 0; mi < 4; ++mi)
            pk.bv[r * 4 + mi] = (bf16_t)acc[mi][ni][r];
        size_t addr = vbase + (size_t)d * S_ + sblk * 64 + quad * 16;
        *(uint4*)&vt_out[addr]     = pk.u[0];
        *(uint4*)&vt_out[addr + 8] = pk.u[1];
      }
    }
  } else {
    float* Cp = (float*)Cbase;
#pragma unroll
    for (int mi = 0; mi < 4; ++mi) {
#pragma unroll
      for (int ni = 0; ni < 4; ++ni)
#pragma unroll
        for (int r = 0; r < 4; ++r)
          Lw[(quad * 4 + r) * 68 + ni * 16 + l16] = acc[mi][ni][r];
      // copy-out: float4 per lane, 256-B segments per 16 lanes
#pragma unroll
      for (int j = 0; j < 4; ++j) {
        int lr = j * 4 + quad;
        f32x4 vv = *(const f32x4*)&Lw[lr * 68 + l16 * 4];
        int rowg = mb + wr * 64 + mi * 16 + lr;
        int colg = nb + wc * 64 + l16 * 4;
        *(f32x4*)&Cp[(size_t)rowg * D_ + colg] = vv;
      }
    }
  }
}

// ---------------- block-sparse flash attention: 2 q-blocks / workgroup ----------------
__global__ __launch_bounds__(256) void attn_kernel(const bf16_t* __restrict__ q,
                                                   const bf16_t* __restrict__ k,
                                                   const bf16_t* __restrict__ vt,
                                                   bf16_t* __restrict__ o) {
  const int m = blockIdx.x, h = blockIdx.y, b = blockIdx.z;
  const int n0 = m * 2, n1 = n0 + 1;
  const int tid = threadIdx.x;
  const int wid = tid >> 6, lane = tid & 63;
  const int quad = lane >> 4, l16 = lane & 15;

  __shared__ bf16_t Ks[64 * 72];
  __shared__ bf16_t Vs[64 * 72];
  __shared__ bf16_t Ps[4][16 * 72];

  const size_t hoff = (size_t)h * HD_;
  const size_t vtbase = (size_t)(b * H_ + h) * HD_ * S_;
  const size_t rowb[2] = {(size_t)(b * S_ + n0 * 64), (size_t)(b * S_ + n1 * 64)};

  bf16x8 aq[2][2];
#pragma unroll
  for (int x = 0; x < 2; ++x) {
    const bf16_t* qr = q + (rowb[x] + wid * 16 + l16) * D_ + hoff;
    aq[x][0] = *(const bf16x8*)(qr + quad * 8);
    aq[x][1] = *(const bf16x8*)(qr + 32 + quad * 8);
  }

  f32x4 o_acc[2][4];
  float lsum[2][4];
#pragma unroll
  for (int x = 0; x < 2; ++x)
#pragma unroll
    for (int t = 0; t < 4; ++t) {
      o_acc[x][t] = (f32x4){0.f, 0.f, 0.f, 0.f};
      lsum[x][t] = 0.f;
    }

  const int srow = tid >> 3;
  const int scol = (tid & 7) * 8;

  const int kb0 = (n0 >= W_ - 1) ? n0 - (W_ - 1) : 0;
  for (int kb = kb0; kb <= n1; ++kb) {
    __syncthreads();
    const size_t krow = (size_t)(b * S_ + kb * 64);
#pragma unroll
    for (int it = 0; it < 2; ++it) {
      int r = it * 32 + srow;
      *(uint4*)&Ks[r * 72 + scol] = *(const uint4*)&k[(krow + r) * D_ + hoff + scol];
      *(uint4*)&Vs[r * 72 + scol] = *(const uint4*)&vt[vtbase + (size_t)r * S_ + kb * 64 + scol];
    }
    __syncthreads();

#pragma unroll
    for (int x = 0; x < 2; ++x) {
      const int nx = n0 + x;
      if (x == 0 ? (kb > n0) : (kb < n1 - (W_ - 1))) continue;  // wave-uniform

      f32x4 sacc[4];
#pragma unroll
      for (int t = 0; t < 4; ++t) sacc[t] = (f32x4){0.f, 0.f, 0.f, 0.f};
#pragma unroll
      for (int t = 0; t < 4; ++t) {
        bf16x8 bk0 = *(const bf16x8*)&Ks[(t * 16 + l16) * 72 + quad * 8];
        bf16x8 bk1 = *(const bf16x8*)&Ks[(t * 16 + l16) * 72 + 32 + quad * 8];
        sacc[t] = __builtin_amdgcn_mfma_f32_16x16x32_bf16(aq[x][0], bk0, sacc[t], 0, 0, 0);
        sacc[t] = __builtin_amdgcn_mfma_f32_16x16x32_bf16(aq[x][1], bk1, sacc[t], 0, 0, 0);
      }

      const bool diag = (kb == nx);
#pragma unroll
      for (int r = 0; r < 4; ++r) {
        int qpos = wid * 16 + quad * 4 + r;
        union { bf16_t bv[4]; uint2 u; } pk;
        float rs = 0.f;
#pragma unroll
        for (int t = 0; t < 4; ++t) {
          float p = __builtin_exp2f(sacc[t][r]);
          if (diag && (t * 16 + l16 > qpos)) p = 0.f;
          rs += p;
          pk.bv[t] = (bf16_t)p;
        }
        lsum[x][r] += rs;
        *(uint2*)&Ps[wid][(quad * 4 + r) * 72 + l16 * 4] = pk.u;   // col' = pi(key)
      }

      bf16x8 pa0 = *(const bf16x8*)&Ps[wid][l16 * 72 + quad * 8];
      bf16x8 pa1 = *(const bf16x8*)&Ps[wid][l16 * 72 + 32 + quad * 8];
#pragma unroll
      for (int t = 0; t < 4; ++t) {
        bf16x8 vb0 = *(const bf16x8*)&Vs[(t * 16 + l16) * 72 + quad * 8];
        bf16x8 vb1 = *(const bf16x8*)&Vs[(t * 16 + l16) * 72 + 32 + quad * 8];
        o_acc[x][t] = __builtin_amdgcn_mfma_f32_16x16x32_bf16(pa0, vb0, o_acc[x][t], 0, 0, 0);
        o_acc[x][t] = __builtin_amdgcn_mfma_f32_16x16x32_bf16(pa1, vb1, o_acc[x][t], 0, 0, 0);
      }
    }
  }

#pragma unroll
  for (int x = 0; x < 2; ++x) {
    float inv[4];
#pragma unroll
    for (int r = 0; r < 4; ++r) {
      float s = lsum[x][r];
#pragma unroll
      for (int off = 1; off < 16; off <<= 1) s += __shfl_xor(s, off);
      inv[r] = 1.f / s;
    }
#pragma unroll
    for (int t = 0; t < 4; ++t)
#pragma unroll
      for (int r = 0; r < 4; ++r) {
        int row = wid * 16 + quad * 4 + r;
        int col = t * 16 + l16;
        o[(rowb[x] + row) * D_ + hoff + col] = (bf16_t)(o_acc[x][t][r] * inv[r]);
      }
  }
}

// ---------------- launch ----------------
extern "C" void kernel_launch(void* const* d_in, const int* in_sizes, int n_in,
                              void* d_out, int out_size, void* d_ws, size_t ws_size,
                              hipStream_t stream) {
  const float* hs = (const float*)d_in[0];
  const int* pos  = (const int*)d_in[1];
  const float* wq = (const float*)d_in[2];
  const float* wk = (const float*)d_in[3];
  const float* wv = (const float*)d_in[4];
  const float* wo = (const float*)d_in[5];

  bf16_t* ws   = (bf16_t*)d_ws;
  bf16_t* hsb  = ws;                          // M_*D_
  bf16_t* wT   = hsb + (size_t)M_ * D_;       // 4*D_*D_
  bf16_t* qkv  = wT + (size_t)4 * D_ * D_;    // 3*M_*D_ (q, k, vt slots)
  bf16_t* attn = qkv + (size_t)3 * M_ * D_;   // M_*D_
  bf16_t* qw  = qkv;
  bf16_t* kw  = qkv + (size_t)M_ * D_;
  bf16_t* vtg = qkv + (size_t)2 * M_ * D_;    // V transposed (written by gemm z=2 epilogue)

  cast_bf16_kernel<<<(M_ * D_ / 4 + 255) / 256, 256, 0, stream>>>(hs, hsb, M_ * D_ / 4);
  transpose_cast_kernel<<<dim3(D_ / 32, D_ / 32, 4), dim3(32, 8), 0, stream>>>(wq, wk, wv, wo, wT);
  gemm128<true><<<dim3(D_ / 128, M_ / 128, 3), 256, 0, stream>>>(hsb, wT, (void*)qkv, vtg, pos);
  attn_kernel<<<dim3(NB_ / 2, H_, B_), 256, 0, stream>>>(qw, kw, vtg, attn);
  gemm128<false><<<dim3(D_ / 128, M_ / 128, 1), 256, 0, stream>>>(attn, wT + (size_t)3 * D_ * D_, d_out, nullptr, pos);
}